// Round 14
// baseline (275.008 us; speedup 1.0000x reference)
//
#include <hip/hip_runtime.h>

#define HH 384
#define WW 384
#define OUTD 370
#define NSHIFT 99

// ---- fused per-tile geometry: 32 wide x 24 tall (R13, measured 190us) ----
// 192 tiles x 4 batch = 768 blocks = exactly 3/CU; no grid barrier (per-tile dep).
// Bank law: per-32-lane-phase bijection required. This round: horiz packs row-pairs
// (r, r+15) into v2f (same window addressing both rows -> natural packed operands);
// vert packs images {P,G}. P-units tid 0..119, G-units tid 128..247 -> no phase
// mixes images (fixes R13's 3.4e6 conflicts from the straddling phase).
#define TW 32
#define TH 24
#define LSTR 47          // L stride (==15 mod 32)
#define LROWS 39         // 24 + 6 conv + 9 shift span
#define LPADSZ 1856      // 39*47=1833 padded to 32-mult -> LG/tT bases bank-aligned
#define TMS 31           // tmp_T stride (==-1 mod 32); rows r and r+15 -> ds_write2
#define TTSZ (TW * TMS)  // 992 (32-mult)
#define NXT 12
#define NYT 16

#define G0 0.32465246735834974f   // exp(-9/8)
#define G1 0.6065306597126334f    // exp(-4/8)
#define G2 0.8824969025845955f    // exp(-1/8)
#define KS 0.039788735772973836f  // 1/(8*pi)
#define LOG2E 1.4426950408889634f

typedef float v2f __attribute__((ext_vector_type(2)));

__device__ __forceinline__ void shift_of(int s, int& sx, int& sy)
{
    int t = (s < 55) ? s : s + 1;    // skip (0,0)
    sx = t / 10 - 5;
    sy = t - (t / 10) * 10 - 5;
}

__device__ __forceinline__ void load_tile(const float* __restrict__ img,
                                          int oy0, int ox0, float* L, int tid)
{
    for (int i = tid; i < LROWS * LSTR; i += 256) {
        int r = i / LSTR, c = i - r * LSTR;
        int gr = oy0 + r; if (gr >= HH) gr -= HH;   // circular wrap
        int gc = ox0 + c; if (gc >= WW) gc -= WW;
        L[i] = img[gr * WW + gc];
    }
}

// horizontal 7-tap over inline diff^2, ROW-PAIR packed: rows (r0, r0+15) share one
// window decode; 4 output columns. All arithmetic on v2f -> v_pk_*_f32.
__device__ __forceinline__ void horiz4x2(const float* __restrict__ Lb,
                                         const v2f* __restrict__ cA,
                                         float* __restrict__ tb,
                                         int r0, int c0, int sx, int sy)
{
    const float* Ls0 = &Lb[(r0 + 4 - sy) * LSTR + (c0 + 4 - sx)];
    const float* Ls1 = Ls0 + 15 * LSTR;
    v2f v[10];
#pragma unroll
    for (int j = 0; j < 10; ++j) {
        v2f s; s.x = Ls0[j]; s.y = Ls1[j];   // contiguous per row -> ds_read2
        v2f d = cA[j] - s;
        v[j] = d * d;
    }
    float* o = &tb[c0 * TMS + r0];
#pragma unroll
    for (int k = 0; k < 4; ++k) {
        v2f t = G0 * (v[k] + v[k + 6]) + G1 * (v[k + 1] + v[k + 5]) +
                G2 * (v[k + 2] + v[k + 4]) + v[k + 3];
        o[k * TMS] = t.x;                    // offsets r0, r0+15 -> one ds_write2
        o[k * TMS + 15] = t.y;
    }
}

// vertical 7-tap, IMAGE-packed {P,G}: 3 outputs from 9 consecutive tmp_T values
__device__ __forceinline__ void vert3p(const float* __restrict__ tP,
                                       const float* __restrict__ tG,
                                       int vx, int vy0, v2f* D)
{
    const float* a = &tP[vx * TMS + vy0];
    const float* b = &tG[vx * TMS + vy0];
    v2f w[9];
#pragma unroll
    for (int j = 0; j < 9; ++j) { w[j].x = a[j]; w[j].y = b[j]; }
#pragma unroll
    for (int k = 0; k < 3; ++k)
        D[k] = KS * (G0 * (w[k] + w[k + 6]) + G1 * (w[k + 1] + w[k + 5]) +
                     G2 * (w[k + 2] + w[k + 4]) + w[k + 3]);
}

extern "C" __global__ void __launch_bounds__(256, 3)
mind_fused(const float* __restrict__ pred, const float* __restrict__ gt,
           float* __restrict__ out)
{
    __shared__ float LP[LPADSZ];
    __shared__ float LG[LPADSZ];
    __shared__ float tTP[2][TTSZ];
    __shared__ float tTG[2][TTSZ];
    __shared__ float wred[4];
    const int tid = threadIdx.x;
    const int b = blockIdx.y;
    const int oy0 = ((int)blockIdx.x / NXT) * TH;
    const int ox0 = ((int)blockIdx.x % NXT) * TW;

    load_tile(pred + (size_t)b * HH * WW, oy0, ox0, LP, tid);
    load_tile(gt   + (size_t)b * HH * WW, oy0, ox0, LG, tid);

    // horiz units: 15 row-pairs x 8 col-quads per image. P: tid 0..119, G: 128..247.
    const bool hP = tid < 120;
    const bool hG = (tid >= 128) && (tid < 248);
    const bool hasH = hP || hG;
    const int hu = hP ? tid : (tid - 128);
    const int pr = hu >> 3;              // row-pair base row 0..14 (other row +15)
    const int hc0 = (hu & 7) << 2;       // col quad 0,4,..,28
    const float* Lh = hG ? LG : LP;
    float* const tb0 = hG ? tTG[0] : tTP[0];
    float* const tb1 = hG ? tTG[1] : tTP[1];

    // vert units: all 256 = 32 cols x 8 strips of 3 rows, both images packed
    const int vx = tid & 31, vy0 = (tid >> 5) * 3;

    __syncthreads();

    v2f cA[10];
    if (hasH) {
        const float* p0 = &Lh[(pr + 4) * LSTR + hc0 + 4];
        const float* p1 = p0 + 15 * LSTR;
#pragma unroll
        for (int j = 0; j < 10; ++j) { cA[j].x = p0[j]; cA[j].y = p1[j]; }
    }

    // ---- phase 1: V (4 cardinals) and minD over 99 shifts, both images ----
    v2f dm[3], vs[3];
#pragma unroll
    for (int k = 0; k < 3; ++k) { dm[k] = (v2f)(1e30f); vs[k] = (v2f)(0.f); }

    for (int s = 0; s < NSHIFT; ++s) {
        int sx, sy; shift_of(s, sx, sy);
        if (hasH) horiz4x2(Lh, cA, (s & 1) ? tb1 : tb0, pr, hc0, sx, sy);
        __syncthreads();   // tT[s&1] ready; buffer alternation -> WAR safe
        v2f D[3];
        vert3p(tTP[s & 1], tTG[s & 1], vx, vy0, D);
        const bool card = (sx * sx + sy * sy) == 1;
#pragma unroll
        for (int k = 0; k < 3; ++k) {
            dm[k].x = fminf(dm[k].x, D[k].x);
            dm[k].y = fminf(dm[k].y, D[k].y);
            if (card) vs[k] += D[k];
        }
    }

    v2f rv[3];
    bool valid[3];
#pragma unroll
    for (int k = 0; k < 3; ++k) {
        int oy = oy0 + vy0 + k, ox = ox0 + vx;
        valid[k] = (oy < OUTD) && (ox < OUTD);
        rv[k].x = LOG2E / (vs[k].x * 0.25f + 1e-5f);
        rv[k].y = LOG2E / (vs[k].y * 0.25f + 1e-5f);
    }

    __syncthreads();   // phase boundary: protect buf-0 reuse against last vert read

    // ---- phase 2: recompute D, accumulate |exp2((m-D)*rv)p - (...)g| ----
    float acc = 0.f;
    for (int s = 0; s < NSHIFT; ++s) {
        int sx, sy; shift_of(s, sx, sy);
        if (hasH) horiz4x2(Lh, cA, (s & 1) ? tb1 : tb0, pr, hc0, sx, sy);
        __syncthreads();
        v2f D[3];
        vert3p(tTP[s & 1], tTG[s & 1], vx, vy0, D);
#pragma unroll
        for (int k = 0; k < 3; ++k) {
            if (valid[k]) {
                float ep = exp2f((dm[k].x - D[k].x) * rv[k].x);
                float eg = exp2f((dm[k].y - D[k].y) * rv[k].y);
                acc += fabsf(ep - eg);
            }
        }
    }

#pragma unroll
    for (int off = 32; off > 0; off >>= 1) acc += __shfl_down(acc, off, 64);
    const int lane = tid & 63, wv = tid >> 6;
    if (lane == 0) wred[wv] = acc;
    __syncthreads();
    if (tid == 0) {
        const float SC = (float)(1.0 / 54212400.0);  // 1/(4*370*370*99)
        atomicAdd(out, (wred[0] + wred[1] + wred[2] + wred[3]) * SC);
    }
}

extern "C" void kernel_launch(void* const* d_in, const int* in_sizes, int n_in,
                              void* d_out, int out_size, void* d_ws, size_t ws_size,
                              hipStream_t stream)
{
    (void)in_sizes; (void)n_in; (void)out_size; (void)d_ws; (void)ws_size;
    const float* pred = (const float*)d_in[0];
    const float* gt   = (const float*)d_in[1];
    float* out = (float*)d_out;

    hipMemsetAsync(d_out, 0, sizeof(float), stream);

    dim3 g(NXT * NYT, 4, 1);   // 192 tiles x 4 batch = 768 blocks = 3/CU exact
    mind_fused<<<g, 256, 0, stream>>>(pred, gt, out);
}

// Round 15
// 219.488 us; speedup vs baseline: 1.2529x; 1.2529x over previous
//
#include <hip/hip_runtime.h>

#define HH 384
#define WW 384
#define OUTD 370
#define NSHIFT 99

// ---- fused per-tile geometry: 32 wide x 24 tall (R13, measured 190us/90% VALU) ----
// 192 tiles x 4 batch = 768 blocks = exactly 3/CU; per-tile fusion, no grid barrier.
// Bank law: conflicts are per 32-lane phase; (stride mod 32, decode) must biject
// each phase onto the banks. Horiz P-units tid 0..119, G-units tid 128..247 ->
// every phase is single-image, residues 15*hr+8*oct bijective (R14-verified: 0 conflicts).
// Scalar VALU only -- packed v2f failed twice (R6, R14: pack-assembly movs + strided
// DS reads beat the pk gain).
#define TW 32
#define TH 24
#define LSTR 47          // L stride (==15 mod 32)
#define LROWS 39         // 24 + 6 conv + 9 shift span
#define LPADSZ 1856      // 39*47=1833 padded to 32-mult -> LG base bank-aligned
#define TMS 31           // tmp_T stride (==-1 mod 32)
#define TTSZ (TW * TMS)  // 992 (32-mult)
#define NXT 12
#define NYT 16

#define G0 0.32465246735834974f   // exp(-9/8)
#define G1 0.6065306597126334f    // exp(-4/8)
#define G2 0.8824969025845955f    // exp(-1/8)
#define KS 0.039788735772973836f  // 1/(8*pi)
#define LOG2E 1.4426950408889634f

__device__ __forceinline__ float tap7(const float* v)
{
    return fmaf(G0, v[0] + v[6],
           fmaf(G1, v[1] + v[5],
           fmaf(G2, v[2] + v[4], v[3])));
}

__device__ __forceinline__ void shift_of(int s, int& sx, int& sy)
{
    int t = (s < 55) ? s : s + 1;    // skip (0,0)
    sx = t / 10 - 5;
    sy = t - (t / 10) * 10 - 5;
}

__device__ __forceinline__ void load_tile(const float* __restrict__ img,
                                          int oy0, int ox0, float* L, int tid)
{
    for (int i = tid; i < LROWS * LSTR; i += 256) {
        int r = i / LSTR, c = i - r * LSTR;
        int gr = oy0 + r; if (gr >= HH) gr -= HH;   // circular wrap
        int gc = ox0 + c; if (gc >= WW) gc -= WW;
        L[i] = img[gr * WW + gc];
    }
}

// horizontal 7-tap over inline diff^2; 8 outputs -> transposed tmp (R13 scalar core)
__device__ __forceinline__ void horiz8(const float* __restrict__ Lb,
                                       const float* __restrict__ cA,
                                       float* __restrict__ tb,
                                       int r, int c0, int sx, int sy)
{
    const float* Ls = &Lb[(r + 4 - sy) * LSTR + (c0 + 4 - sx)];
    float v[14];
#pragma unroll
    for (int t = 0; t < 14; ++t) { float d = cA[t] - Ls[t]; v[t] = d * d; }
    float* o = &tb[c0 * TMS + r];
#pragma unroll
    for (int k = 0; k < 8; ++k) o[k * TMS] = tap7(v + k);
}

// vertical 7-tap, 3 outputs from 9 consecutive tmp_T values (R13 scalar core)
__device__ __forceinline__ void vert3(const float* __restrict__ tT, int vx, int vy0, float* D)
{
    const float* t = &tT[vx * TMS + vy0];
    float w[9];
#pragma unroll
    for (int j = 0; j < 9; ++j) w[j] = t[j];
#pragma unroll
    for (int k = 0; k < 3; ++k) D[k] = KS * tap7(w + k);
}

extern "C" __global__ void __launch_bounds__(256, 3)
mind_fused(const float* __restrict__ pred, const float* __restrict__ gt,
           float* __restrict__ out)
{
    __shared__ float LP[LPADSZ];
    __shared__ float LG[LPADSZ];
    __shared__ float tTP[2][TTSZ];
    __shared__ float tTG[2][TTSZ];
    __shared__ float wred[4];
    const int tid = threadIdx.x;
    const int b = blockIdx.y;
    const int oy0 = ((int)blockIdx.x / NXT) * TH;
    const int ox0 = ((int)blockIdx.x % NXT) * TW;

    load_tile(pred + (size_t)b * HH * WW, oy0, ox0, LP, tid);
    load_tile(gt   + (size_t)b * HH * WW, oy0, ox0, LG, tid);

    // horiz: 120 units/image = 30 rows x 4 col-octets. PURE phases:
    // P on tid 0..119, G on tid 128..247 (no 32-lane phase mixes images).
    const bool hP = tid < 120;
    const bool hG = (tid >= 128) && (tid < 248);
    const bool hasH = hP || hG;
    const int hu = hP ? tid : (tid - 128);
    const int hr = hu >> 2, hc0 = (hu & 3) << 3;
    const float* Lh = hG ? LG : LP;
    float* const tb0 = hG ? tTG[0] : tTP[0];
    float* const tb1 = hG ? tTG[1] : tTP[1];

    // vert: all 256 = 32 cols x 8 strips of 3 rows, both images per thread
    const int vx = tid & 31, vy0 = (tid >> 5) * 3;

    __syncthreads();

    float cA[14];
    if (hasH) {
        const float* p = &Lh[(hr + 4) * LSTR + hc0 + 4];
#pragma unroll
        for (int t = 0; t < 14; ++t) cA[t] = p[t];
    }

    // ---- phase 1: V (4 cardinals) and minD over 99 shifts, both images ----
    float dmp[3], vsp[3], dmg[3], vsg[3];
#pragma unroll
    for (int k = 0; k < 3; ++k) { dmp[k] = 1e30f; vsp[k] = 0.f; dmg[k] = 1e30f; vsg[k] = 0.f; }

    for (int s = 0; s < NSHIFT; ++s) {
        int sx, sy; shift_of(s, sx, sy);
        if (hasH) horiz8(Lh, cA, (s & 1) ? tb1 : tb0, hr, hc0, sx, sy);
        __syncthreads();   // tT[s&1] ready; buffer alternation -> WAR safe
        float Dp[3], Dg[3];
        vert3(tTP[s & 1], vx, vy0, Dp);
        vert3(tTG[s & 1], vx, vy0, Dg);
        const bool card = (sx * sx + sy * sy) == 1;
#pragma unroll
        for (int k = 0; k < 3; ++k) {
            dmp[k] = fminf(dmp[k], Dp[k]);
            dmg[k] = fminf(dmg[k], Dg[k]);
            if (card) { vsp[k] += Dp[k]; vsg[k] += Dg[k]; }
        }
    }

    // loss constants; invalid pixels get rv=0 -> ep=eg=exp2(0)=1 -> |ep-eg|=0
    // exactly, so the phase-2 loop is fully branchless.
    float rvp[3], rvg[3];
#pragma unroll
    for (int k = 0; k < 3; ++k) {
        int oy = oy0 + vy0 + k, ox = ox0 + vx;
        const bool valid = (oy < OUTD) && (ox < OUTD);
        rvp[k] = valid ? LOG2E / (vsp[k] * 0.25f + 1e-5f) : 0.f;
        rvg[k] = valid ? LOG2E / (vsg[k] * 0.25f + 1e-5f) : 0.f;
    }

    __syncthreads();   // phase boundary: protect buf-0 reuse against last vert read

    // ---- phase 2: recompute D, accumulate |exp2((m-D)*rv)p - (...)g| ----
    float acc = 0.f;
    for (int s = 0; s < NSHIFT; ++s) {
        int sx, sy; shift_of(s, sx, sy);
        if (hasH) horiz8(Lh, cA, (s & 1) ? tb1 : tb0, hr, hc0, sx, sy);
        __syncthreads();
        float Dp[3], Dg[3];
        vert3(tTP[s & 1], vx, vy0, Dp);
        vert3(tTG[s & 1], vx, vy0, Dg);
#pragma unroll
        for (int k = 0; k < 3; ++k) {
            float ep = exp2f((dmp[k] - Dp[k]) * rvp[k]);
            float eg = exp2f((dmg[k] - Dg[k]) * rvg[k]);
            acc += fabsf(ep - eg);
        }
    }

#pragma unroll
    for (int off = 32; off > 0; off >>= 1) acc += __shfl_down(acc, off, 64);
    const int lane = tid & 63, wv = tid >> 6;
    if (lane == 0) wred[wv] = acc;
    __syncthreads();
    if (tid == 0) {
        const float SC = (float)(1.0 / 54212400.0);  // 1/(4*370*370*99)
        atomicAdd(out, (wred[0] + wred[1] + wred[2] + wred[3]) * SC);
    }
}

extern "C" void kernel_launch(void* const* d_in, const int* in_sizes, int n_in,
                              void* d_out, int out_size, void* d_ws, size_t ws_size,
                              hipStream_t stream)
{
    (void)in_sizes; (void)n_in; (void)out_size; (void)d_ws; (void)ws_size;
    const float* pred = (const float*)d_in[0];
    const float* gt   = (const float*)d_in[1];
    float* out = (float*)d_out;

    hipMemsetAsync(d_out, 0, sizeof(float), stream);

    dim3 g(NXT * NYT, 4, 1);   // 192 tiles x 4 batch = 768 blocks = 3/CU exact
    mind_fused<<<g, 256, 0, stream>>>(pred, gt, out);
}